// Round 1
// baseline (549.479 us; speedup 1.0000x reference)
//
#include <hip/hip_runtime.h>
#include <math.h>

#define Lseq 256
#define Bn   32
#define Cn   64
#define WIN  22   // decay window: exp(-22^2/8) = 5e-27, far below fp32 noise

__global__ void zero_loss_kernel(float* p) { *p = 0.0f; }

// Process one 64x64 matrix for one (l,b):
//   einsum A (cols): outA[c] += wA * sum_r vrow[r] * M[r][c]
//   einsum B (rows): outB[r] += wB * sum_c M[r][c] * vcol[c]
// Reads M exactly once with coalesced float4 loads.
__device__ __forceinline__ void mat_pass(
    const float4* __restrict__ M4,
    const float* __restrict__ vrow, const float* __restrict__ vcol,
    float* outA, float* outB, float wA, float wB,
    float* stage /*1024 floats, float4-aligned*/, int tid)
{
  const int cb = tid & 15;   // column block (4 cols)
  const int m  = tid >> 4;   // row-chunk id 0..15
  const float vc0 = vcol[4*cb+0], vc1 = vcol[4*cb+1];
  const float vc2 = vcol[4*cb+2], vc3 = vcol[4*cb+3];
  float pA0 = 0.f, pA1 = 0.f, pA2 = 0.f, pA3 = 0.f;
  float pB[4];
#pragma unroll
  for (int k = 0; k < 4; ++k) {
    float4 v = M4[tid + 256*k];       // row r = m + 16k, cols 4cb..4cb+3
    float vr = vrow[m + 16*k];
    pA0 += vr * v.x; pA1 += vr * v.y; pA2 += vr * v.z; pA3 += vr * v.w;
    pB[k] = v.x*vc0 + v.y*vc1 + v.z*vc2 + v.w*vc3;
  }
  // stage column partials (float4 -> conflict-free ds_write_b128)
  reinterpret_cast<float4*>(stage)[m*16 + cb] = make_float4(pA0, pA1, pA2, pA3);
  // reduce row partials across the 16 lanes sharing this row set
#pragma unroll
  for (int k = 0; k < 4; ++k) {
#pragma unroll
    for (int off = 8; off >= 1; off >>= 1)
      pB[k] += __shfl_xor(pB[k], off, 64);
  }
  if (cb == 0) {
#pragma unroll
    for (int k = 0; k < 4; ++k)
      outB[m + 16*k] += wB * pB[k];   // each row has exactly one writer
  }
  __syncthreads();
  if (tid < 64) {
    float acc = 0.f;
#pragma unroll
    for (int mm = 0; mm < 16; ++mm) acc += stage[mm*64 + tid];
    outA[tid] += wA * acc;
  }
  __syncthreads();
}

__global__ __launch_bounds__(256) void tf_criterion_kernel(
    const float* __restrict__ f,   const float* __restrict__ s,
    const float* __restrict__ fs,  const float* __restrict__ ff,
    const float* __restrict__ ss,  const float* __restrict__ fs_t,
    const float* __restrict__ sf_t,
    const int* __restrict__ f_labels, const int* __restrict__ s_labels,
    float* __restrict__ out)
{
  __shared__ float4 stage4[256];           // 4 KB staging for column reductions
  __shared__ float f_mp[64], f_mf[64], s_mp[64], s_mf[64];
  __shared__ float prev_f[64], prev_s[64];
  __shared__ float nf[64], ns[64];         // accumulated deltas for next_f/next_s
  __shared__ float lp[4];

  const int tid = threadIdx.x;
  const int lb  = blockIdx.x;              // lb = l*B + b
  const int l   = lb >> 5;
  const int b   = lb & 31;

  // ---- phase 0: message vectors (windowed decay matvec) + prev rows ----
  if (tid < 128) {
    const int which = tid >> 6;            // 0: f, 1: s
    const int c     = tid & 63;
    const float* src = which ? s : f;
    float mp = 0.f, mf = 0.f, pv = 0.f;
    int i0 = l - WIN; if (i0 < 0) i0 = 0;
    int i1 = l + WIN; if (i1 > Lseq - 1) i1 = Lseq - 1;
    for (int i = i0; i <= i1; ++i) {
      float x = src[((size_t)i * Bn + b) * Cn + c];
      int d = l - i;
      if (d == 0) { pv = x; continue; }
      float w = expf(-0.125f * (float)(d * d));
      if (d > 0) mp += w * x; else mf += w * x;
    }
    mp *= 1.0f / (float)((l > 1) ? l : 1);
    mf *= 1.0f / (float)((Lseq - 1 - l > 1) ? (Lseq - 1 - l) : 1);
    if (which == 0) { f_mp[c] = mp; f_mf[c] = mf; prev_f[c] = pv; }
    else            { s_mp[c] = mp; s_mf[c] = mf; prev_s[c] = pv; }
  } else if (tid < 192) {
    nf[tid - 128] = 0.f;
  } else {
    ns[tid - 192] = 0.f;
  }
  __syncthreads();

  // ---- phase 1: stream the five 64x64 matrices, each read exactly once ----
  float* stage = reinterpret_cast<float*>(stage4);
  const size_t mo = (size_t)lb * 4096;
  // ff:   A: f_mp . ff -> nf (W_T)      B: ff . f_mf -> nf (W_T)
  mat_pass((const float4*)(ff   + mo), f_mp,   f_mf,   nf, nf, 0.5f, 0.5f, stage, tid);
  // ss:   A: s_mp . ss -> ns            B: ss . s_mf -> ns
  mat_pass((const float4*)(ss   + mo), s_mp,   s_mf,   ns, ns, 0.5f, 0.5f, stage, tid);
  // sf_t [s,f]: A: s_mp . M -> nf       B: M . f_mf -> ns
  mat_pass((const float4*)(sf_t + mo), s_mp,   f_mf,   nf, ns, 0.5f, 0.5f, stage, tid);
  // fs_t [f,s]: A: f_mp . M -> ns       B: M . s_mf -> nf
  mat_pass((const float4*)(fs_t + mo), f_mp,   s_mf,   ns, nf, 0.5f, 0.5f, stage, tid);
  // fs [f,s]:   A: prev_f . M -> ns (W_S)  B: M . prev_s -> nf (W_S)
  mat_pass((const float4*)(fs   + mo), prev_f, prev_s, ns, nf, 0.5f, 0.5f, stage, tid);

  // ---- epilogue: softmax outputs + 4 cross-entropy row contributions ----
  const int w = tid >> 6;   // wave id: 0=f, 1=s, 2=next_f, 3=next_s
  const int c = tid & 63;
  float x;
  if      (w == 0) x = prev_f[c];
  else if (w == 1) x = prev_s[c];
  else if (w == 2) x = prev_f[c] + nf[c];
  else             x = prev_s[c] + ns[c];

  float mx = x;
#pragma unroll
  for (int off = 32; off >= 1; off >>= 1)
    mx = fmaxf(mx, __shfl_xor(mx, off, 64));
  float e  = expf(x - mx);
  float sm = e;
#pragma unroll
  for (int off = 32; off >= 1; off >>= 1)
    sm += __shfl_xor(sm, off, 64);

  if      (w == 2) out[(size_t)lb * 64 + c]          = e / sm;
  else if (w == 3) out[524288 + (size_t)lb * 64 + c] = e / sm;

  float lse = logf(sm) + mx;
  int lab = (w & 1) ? s_labels[lb] : f_labels[lb];
  if (c == lab) lp[w] = lse - x;
  __syncthreads();
  if (tid == 0)
    atomicAdd(out + 1048576, (lp[0] + lp[1] + lp[2] + lp[3]) * (1.0f / 8192.0f));
}

extern "C" void kernel_launch(void* const* d_in, const int* in_sizes, int n_in,
                              void* d_out, int out_size, void* d_ws, size_t ws_size,
                              hipStream_t stream) {
  const float* f     = (const float*)d_in[0];
  const float* s     = (const float*)d_in[1];
  const float* fs    = (const float*)d_in[2];
  const float* ff    = (const float*)d_in[3];
  const float* ss    = (const float*)d_in[4];
  const float* fs_t  = (const float*)d_in[5];
  const float* sf_t  = (const float*)d_in[6];
  const int*   f_lab = (const int*)d_in[7];
  const int*   s_lab = (const int*)d_in[8];
  float* out = (float*)d_out;

  zero_loss_kernel<<<1, 1, 0, stream>>>(out + 1048576);
  tf_criterion_kernel<<<Lseq * Bn, 256, 0, stream>>>(
      f, s, fs, ff, ss, fs_t, sf_t, f_lab, s_lab, out);
}